// Round 19
// baseline (26.307 us; speedup 1.0000x reference)
//
#include <hip/hip_runtime.h>
#include <hip/hip_bf16.h>

#define B_   32
#define N_   128
#define AH_  512
#define AW_  512
#define LCAP 64    // per-chunk list capacity (one 64-box ballot chunk)
#define LN2  0.69314718055994530942f

// compiler-only reordering fence; one wave's DS ops execute in issue order
#define CFENCE() asm volatile("" ::: "memory")

typedef __fp16 h4_t __attribute__((ext_vector_type(4)));

// ---------------------------------------------------------------------------
// R19 = R17 (best, 24.4us) with the mask stored as F16 (single change).
// R16(2rows,8w/SIMD)=27.0, R17(4rows,4w/SIMD)=24.4, R18(8rows,2w/SIMD)=25.8:
// 4-row amortization is the optimum, and R17 is LDS-capped (20KB -> 8
// blocks/CU = 16 waves/CU). f16 mask halves mask LDS: 12.3KB/block ->
// 13 blocks/CU = 26 waves/CU, 1.6x the latency hiding, at the cost of
// ~100 extra cvt VALU/wave. Mask in [0,1]: f16 rel err <= 4.9e-4 ->
// loss error ~1.5e-3, 13x under the 2e-2 threshold; zeros exact.
// Everything else R17 verbatim.
// ---------------------------------------------------------------------------
__global__ __launch_bounds__(128) void row_bce_kernel(
    const float* __restrict__ att,
    const float* __restrict__ bboxs,
    const int*   __restrict__ img_h_p,
    const int*   __restrict__ img_w_p,
    float*       __restrict__ wave_sums)
{
    const int t    = threadIdx.x;
    const int lane = t & 63;
    const int wid  = t >> 6;                    // 0..1
    const int task = (blockIdx.x << 1) | wid;   // 0..4095
    const int b    = task >> 7;                 // 128 tasks per image
    const int y0   = (task & 127) << 2;         // rows y0..y0+3

    __shared__ float4 s_geo[2][LCAP];           // {pack(x1,x2,ab), x1m, x2m, -}
    __shared__ float4 s_rv [2][LCAP];           // {rv0, rv1, rv2, rv3}
    __shared__ __align__(16) __fp16 s_mask[2][4][AW_];   // 8 KB total

    // ---- att loads FIRST (proven ordering) ----
    const float4* p4 = (const float4*)(att + ((size_t)b * AH_ + y0) * AW_);
    float4 P[4][2];
    #pragma unroll
    for (int r = 0; r < 4; ++r)
        #pragma unroll
        for (int h = 0; h < 2; ++h)
            P[r][h] = p4[r * 128 + h * 64 + lane];

    const float fw  = (float)(*img_w_p);
    const float fh  = (float)(*img_h_p);
    const float sxs = (float)AW_ / fw;
    const float sys = (float)AH_ / fh;

    // ---- box geometry, once per wave (boxes lane and lane+64) ----
    bool   act_any[2];
    int    actb[2];
    int    gx1[2], gx2[2];
    float  gx1m[2], gx2m[2];
    float4 grv[2];
    #pragma unroll
    for (int k = 0; k < 2; ++k) {
        const int n = lane + 64 * k;
        const float* bp = bboxs + ((size_t)b * N_ + n) * 5;
        const float c0 = bp[0], c1 = bp[1], c2 = bp[2], c3 = bp[3], lab = bp[4];
        const bool valid = (lab != -1.0f) && (c0 <= fw) && (c1 <= fh)
                                          && (c2 <= fw) && (c3 <= fh);
        const float bx1 = c0 * sxs, by1 = c1 * sys;
        const float bx2 = c2 * sxs, by2 = c3 * sys;
        const float fx1 = floorf(bx1), fy1 = floorf(by1);
        const float x1m = fx1 + 1.0f - bx1;
        const float y1m = fy1 + 1.0f - by1;
        const float x2m = bx2 - floorf(bx2);
        const float y2m = by2 - floorf(by2);
        const int x1 = (int)fmaxf(fx1, 0.0f);
        const int y1 = (int)fmaxf(fy1, 0.0f);
        const int x2 = (int)fminf(ceilf(bx2) + 1.0f, (float)AW_);
        const int y2 = (int)fminf(ceilf(by2) + 1.0f, (float)AH_);
        gx1[k] = x1; gx2[k] = x2; gx1m[k] = x1m; gx2m[k] = x2m;

        int   ab = 0;
        float rv[4];
        #pragma unroll
        for (int r = 0; r < 4; ++r) {
            const int y = y0 + r;
            const bool a = valid && (y >= y1) && (y < y2);
            ab |= a ? (1 << r) : 0;
            rv[r] = ((y == y1)     ? y1m : 1.0f)
                  * ((y == y2 - 1) ? y2m : 1.0f);
        }
        grv[k]     = make_float4(rv[0], rv[1], rv[2], rv[3]);
        actb[k]    = ab;
        act_any[k] = (ab != 0) && (x1 < x2);
    }

    const unsigned long long ltm  = (1ull << lane) - 1ull;
    const unsigned long long bal0 = __ballot(act_any[0]);
    const unsigned long long bal1 = __ballot(act_any[1]);
    const bool have = (bal0 | bal1) != 0ull;

    __fp16* m0 = s_mask[wid][0];
    __fp16* m1 = s_mask[wid][1];
    __fp16* m2 = s_mask[wid][2];
    __fp16* m3 = s_mask[wid][3];

    if (have) {
        // zero all 4 f16 mask rows (4KB/wave): 4x ds_write_b128 per lane
        float4* mz = (float4*)s_mask[wid];
        const float4 z = make_float4(0.f, 0.f, 0.f, 0.f);
        #pragma unroll
        for (int q = 0; q < 4; ++q) mz[lane + 64 * q] = z;
        CFENCE();

        // ---- two 64-box chunks in index order; list buffer reused ----
        #pragma unroll
        for (int k = 0; k < 2; ++k) {
            const unsigned long long bal = (k == 0) ? bal0 : bal1;
            const int cnt = __popcll(bal);
            if (cnt == 0) continue;
            if (act_any[k]) {
                const int slot = __popcll(bal & ltm);
                s_geo[wid][slot] = make_float4(
                    __int_as_float(gx1[k] | (gx2[k] << 10) | (actb[k] << 20)),
                    gx1m[k], gx2m[k], 0.0f);
                s_rv[wid][slot] = grv[k];
            }
            CFENCE();   // compaction writes precede list reads (in-order DS)

            // raster with 1-deep prefetch; branchless uniform span loop
            float4 g_cur = s_geo[wid][0];
            float4 v_cur = s_rv[wid][0];
            for (int j = 0; j < cnt; ++j) {
                const float4 g = g_cur;
                const float4 v = v_cur;
                if (j + 1 < cnt) {
                    g_cur = s_geo[wid][j + 1];
                    v_cur = s_rv[wid][j + 1];
                }
                const int px = __builtin_amdgcn_readfirstlane(__float_as_int(g.x));
                const int e1 = px & 1023;
                const int e2 = (px >> 10) & 1023;
                const int ab = px >> 20;
                const int iters = (e2 - e1 + 63) >> 6;       // scalar trip count
                if (ab == 15) {                               // interior band box
                    for (int q = 0; q < iters; ++q) {
                        const int xr = e1 + (q << 6) + lane;
                        const int x  = (xr < e2) ? xr : (e2 - 1);
                        const float edge = ((x == e1)     ? g.y : 1.0f)
                                         * ((x == e2 - 1) ? g.z : 1.0f);
                        m0[x] = (__fp16)(v.x * edge);
                        m1[x] = (__fp16)(v.y * edge);
                        m2[x] = (__fp16)(v.z * edge);
                        m3[x] = (__fp16)(v.w * edge);
                    }
                } else {                                      // band-edge box
                    for (int q = 0; q < iters; ++q) {
                        const int xr = e1 + (q << 6) + lane;
                        const int x  = (xr < e2) ? xr : (e2 - 1);
                        const float edge = ((x == e1)     ? g.y : 1.0f)
                                         * ((x == e2 - 1) ? g.z : 1.0f);
                        if (ab & 1) m0[x] = (__fp16)(v.x * edge);
                        if (ab & 2) m1[x] = (__fp16)(v.y * edge);
                        if (ab & 4) m2[x] = (__fp16)(v.z * edge);
                        if (ab & 8) m3[x] = (__fp16)(v.w * edge);
                    }
                }
            }
            CFENCE();   // raster reads precede next chunk's compaction
        }
    }

    // ---- BCE (ungated, log2 domain; p in [1e-4,1-1e-4]: no clamps) ----
    float acc = 0.0f;
    #pragma unroll
    for (int r = 0; r < 4; ++r) {
        const h4_t* mh4 = (const h4_t*)s_mask[wid][r];
        #pragma unroll
        for (int h = 0; h < 2; ++h) {
            const float4 p = P[r][h];
            float mv[4] = {0.f, 0.f, 0.f, 0.f};
            if (have) {
                const h4_t mm = mh4[h * 64 + lane];   // b64: 4 px of row r
                #pragma unroll
                for (int j = 0; j < 4; ++j) mv[j] = (float)mm[j];
            }
            const float pv[4] = {p.x, p.y, p.z, p.w};
            #pragma unroll
            for (int j = 0; j < 4; ++j) {
                const float lp = __log2f(pv[j]);
                const float l1 = __log2f(1.0f - pv[j]);
                acc += l1 + mv[j] * (lp - l1);
            }
        }
    }
    acc *= LN2;   // one natural-log scale per wave

    // ---- wave reduction -> per-task partial ----
    #pragma unroll
    for (int off = 32; off; off >>= 1) acc += __shfl_down(acc, off, 64);
    if (lane == 0) wave_sums[task] = acc;
}

// ---------------------------------------------------------------------------
// Fused tail: per-image reduce of 128 task partials + any_valid gate +
// batch mean. One block, 1024 threads (32 workers/image); shuffle reductions.
// ---------------------------------------------------------------------------
__global__ __launch_bounds__(1024) void final_kernel(
    const float* __restrict__ bboxs,
    const int*   __restrict__ img_h_p,
    const int*   __restrict__ img_w_p,
    const float* __restrict__ wave_sums,
    float*       __restrict__ out)
{
    const int t = threadIdx.x;
    const int b = t >> 5;        // image 0..31 (two images per 64-lane wave)
    const int j = t & 31;        // worker within image

    __shared__ float s_loss[B_];

    float s = 0.0f;
    #pragma unroll
    for (int k = 0; k < 4; ++k) s += wave_sums[b * 128 + j + 32 * k];

    const float fw = (float)(*img_w_p);
    const float fh = (float)(*img_h_p);
    int av = 0;
    const float* bp = bboxs + (size_t)b * N_ * 5;
    #pragma unroll
    for (int n = j * 4; n < j * 4 + 4; ++n) {
        const float c0 = bp[n * 5 + 0];
        const float c1 = bp[n * 5 + 1];
        const float c2 = bp[n * 5 + 2];
        const float c3 = bp[n * 5 + 3];
        const float lab = bp[n * 5 + 4];
        av |= ((lab != -1.0f) && (c0 <= fw) && (c1 <= fh)
                              && (c2 <= fw) && (c3 <= fh)) ? 1 : 0;
    }

    // reduce the 32 workers of each image (half-wave groups)
    #pragma unroll
    for (int off = 16; off; off >>= 1) {
        s  += __shfl_down(s, off, 64);
        av |= __shfl_down(av, off, 64);
    }
    if (j == 0) s_loss[b] = av ? (-s * (1.0f / (float)(AH_ * AW_))) : 0.0f;
    __syncthreads();

    // batch mean: first wave, all 64 lanes live (upper 32 contribute 0)
    if (t < 64) {
        float v = (t < B_) ? s_loss[t] : 0.0f;
        #pragma unroll
        for (int off = 32; off; off >>= 1) v += __shfl_down(v, off, 64);
        if (t == 0) out[0] = v * (1.0f / (float)B_);
    }
}

extern "C" void kernel_launch(void* const* d_in, const int* in_sizes, int n_in,
                              void* d_out, int out_size, void* d_ws, size_t ws_size,
                              hipStream_t stream)
{
    const float* att   = (const float*)d_in[0];   // (32,1,512,512) f32
    const float* bboxs = (const float*)d_in[1];   // (32,128,5) f32
    const int*   img_h = (const int*)d_in[2];     // scalar
    const int*   img_w = (const int*)d_in[3];     // scalar
    float* out = (float*)d_out;
    float* wave_sums = (float*)d_ws;              // 4096 floats (16 KB)

    row_bce_kernel<<<B_ * AH_ / 8, 128, 0, stream>>>(att, bboxs, img_h, img_w, wave_sums);
    final_kernel<<<1, 1024, 0, stream>>>(bboxs, img_h, img_w, wave_sums, out);
}

// Round 20
// 24.287 us; speedup vs baseline: 1.0831x; 1.0831x over previous
//
#include <hip/hip_runtime.h>
#include <hip/hip_bf16.h>

#define B_   32
#define N_   128
#define AH_  512
#define AW_  512
#define LCAP 64    // per-chunk list capacity (one 64-box ballot chunk)
#define LN2  0.69314718055994530942f

// compiler-only reordering fence; one wave's DS ops execute in issue order
#define CFENCE() asm volatile("" ::: "memory")

// ---------------------------------------------------------------------------
// R20 = R17 VERBATIM (measured best: 24.4us). Revert-to-best after R18 (8-row,
// 25.8), R19 (f16 mask, 26.3) both regressed. Key learned facts baked in:
//  - 4 rows/wave is the amortization optimum (2:27.0, 4:24.4, 8:25.8)
//  - grid = 4096 waves = exactly one resident generation (16 waves/CU);
//    occupancy-capacity levers are dead -- there is no extra work to hide with
//  - att loads FIRST (bbox-first costs +6us)
//  - 2 independent waves/block, no barriers, wave-private LDS
//  - ballot compaction in index order; s_geo+s_rv records, 1-deep prefetch
//  - scalar (readfirstlane) span bounds + clamp loop (branchless)
//  - ungated log2-domain BCE, one x ln2 per wave
//  - shuffle tail; NO grid-wide counter sync (R13: serializes), NO contended
//    atomics (R1: 180us)
// ---------------------------------------------------------------------------
__global__ __launch_bounds__(128) void row_bce_kernel(
    const float* __restrict__ att,
    const float* __restrict__ bboxs,
    const int*   __restrict__ img_h_p,
    const int*   __restrict__ img_w_p,
    float*       __restrict__ wave_sums)
{
    const int t    = threadIdx.x;
    const int lane = t & 63;
    const int wid  = t >> 6;                    // 0..1
    const int task = (blockIdx.x << 1) | wid;   // 0..4095
    const int b    = task >> 7;                 // 128 tasks per image
    const int y0   = (task & 127) << 2;         // rows y0..y0+3

    __shared__ float4 s_geo[2][LCAP];           // {pack(x1,x2,ab), x1m, x2m, -}
    __shared__ float4 s_rv [2][LCAP];           // {rv0, rv1, rv2, rv3}
    __shared__ float  s_mask[2][4][AW_];        // [wid][row][x]

    // ---- att loads FIRST (proven ordering) ----
    const float4* p4 = (const float4*)(att + ((size_t)b * AH_ + y0) * AW_);
    float4 P[4][2];
    #pragma unroll
    for (int r = 0; r < 4; ++r)
        #pragma unroll
        for (int h = 0; h < 2; ++h)
            P[r][h] = p4[r * 128 + h * 64 + lane];

    const float fw  = (float)(*img_w_p);
    const float fh  = (float)(*img_h_p);
    const float sxs = (float)AW_ / fw;
    const float sys = (float)AH_ / fh;

    // ---- box geometry, once per wave (boxes lane and lane+64) ----
    bool   act_any[2];
    int    actb[2];
    int    gx1[2], gx2[2];
    float  gx1m[2], gx2m[2];
    float4 grv[2];
    #pragma unroll
    for (int k = 0; k < 2; ++k) {
        const int n = lane + 64 * k;
        const float* bp = bboxs + ((size_t)b * N_ + n) * 5;
        const float c0 = bp[0], c1 = bp[1], c2 = bp[2], c3 = bp[3], lab = bp[4];
        const bool valid = (lab != -1.0f) && (c0 <= fw) && (c1 <= fh)
                                          && (c2 <= fw) && (c3 <= fh);
        const float bx1 = c0 * sxs, by1 = c1 * sys;
        const float bx2 = c2 * sxs, by2 = c3 * sys;
        const float fx1 = floorf(bx1), fy1 = floorf(by1);
        const float x1m = fx1 + 1.0f - bx1;
        const float y1m = fy1 + 1.0f - by1;
        const float x2m = bx2 - floorf(bx2);
        const float y2m = by2 - floorf(by2);
        const int x1 = (int)fmaxf(fx1, 0.0f);
        const int y1 = (int)fmaxf(fy1, 0.0f);
        const int x2 = (int)fminf(ceilf(bx2) + 1.0f, (float)AW_);
        const int y2 = (int)fminf(ceilf(by2) + 1.0f, (float)AH_);
        gx1[k] = x1; gx2[k] = x2; gx1m[k] = x1m; gx2m[k] = x2m;

        int   ab = 0;
        float rv[4];
        #pragma unroll
        for (int r = 0; r < 4; ++r) {
            const int y = y0 + r;
            const bool a = valid && (y >= y1) && (y < y2);
            ab |= a ? (1 << r) : 0;
            rv[r] = ((y == y1)     ? y1m : 1.0f)
                  * ((y == y2 - 1) ? y2m : 1.0f);
        }
        grv[k]     = make_float4(rv[0], rv[1], rv[2], rv[3]);
        actb[k]    = ab;
        act_any[k] = (ab != 0) && (x1 < x2);
    }

    const unsigned long long ltm  = (1ull << lane) - 1ull;
    const unsigned long long bal0 = __ballot(act_any[0]);
    const unsigned long long bal1 = __ballot(act_any[1]);
    const bool have = (bal0 | bal1) != 0ull;

    float* m0 = s_mask[wid][0];
    float* m1 = s_mask[wid][1];
    float* m2 = s_mask[wid][2];
    float* m3 = s_mask[wid][3];
    float4* mrow4 = (float4*)m0;

    if (have) {
        // zero all 4 mask rows: 8x ds_write_b128 per lane
        const float4 z = make_float4(0.f, 0.f, 0.f, 0.f);
        #pragma unroll
        for (int q = 0; q < 8; ++q) mrow4[lane + 64 * q] = z;
        CFENCE();

        // ---- two 64-box chunks in index order; list buffer reused ----
        #pragma unroll
        for (int k = 0; k < 2; ++k) {
            const unsigned long long bal = (k == 0) ? bal0 : bal1;
            const int cnt = __popcll(bal);
            if (cnt == 0) continue;
            if (act_any[k]) {
                const int slot = __popcll(bal & ltm);
                s_geo[wid][slot] = make_float4(
                    __int_as_float(gx1[k] | (gx2[k] << 10) | (actb[k] << 20)),
                    gx1m[k], gx2m[k], 0.0f);
                s_rv[wid][slot] = grv[k];
            }
            CFENCE();   // compaction writes precede list reads (in-order DS)

            // raster with 1-deep prefetch; branchless uniform span loop
            float4 g_cur = s_geo[wid][0];
            float4 v_cur = s_rv[wid][0];
            for (int j = 0; j < cnt; ++j) {
                const float4 g = g_cur;
                const float4 v = v_cur;
                if (j + 1 < cnt) {
                    g_cur = s_geo[wid][j + 1];
                    v_cur = s_rv[wid][j + 1];
                }
                const int px = __builtin_amdgcn_readfirstlane(__float_as_int(g.x));
                const int e1 = px & 1023;
                const int e2 = (px >> 10) & 1023;
                const int ab = px >> 20;
                const int iters = (e2 - e1 + 63) >> 6;       // scalar trip count
                if (ab == 15) {                               // interior band box
                    for (int q = 0; q < iters; ++q) {
                        const int xr = e1 + (q << 6) + lane;
                        const int x  = (xr < e2) ? xr : (e2 - 1);
                        const float edge = ((x == e1)     ? g.y : 1.0f)
                                         * ((x == e2 - 1) ? g.z : 1.0f);
                        m0[x] = v.x * edge;                   // one vaddr,
                        m1[x] = v.y * edge;                   // +2048/+4096/
                        m2[x] = v.z * edge;                   // +6144 imm offs
                        m3[x] = v.w * edge;
                    }
                } else {                                      // band-edge box
                    for (int q = 0; q < iters; ++q) {
                        const int xr = e1 + (q << 6) + lane;
                        const int x  = (xr < e2) ? xr : (e2 - 1);
                        const float edge = ((x == e1)     ? g.y : 1.0f)
                                         * ((x == e2 - 1) ? g.z : 1.0f);
                        if (ab & 1) m0[x] = v.x * edge;
                        if (ab & 2) m1[x] = v.y * edge;
                        if (ab & 4) m2[x] = v.z * edge;
                        if (ab & 8) m3[x] = v.w * edge;
                    }
                }
            }
            CFENCE();   // raster reads precede next chunk's compaction
        }
    }

    // ---- BCE (ungated, log2 domain; p in [1e-4,1-1e-4]: no clamps) ----
    float acc = 0.0f;
    #pragma unroll
    for (int r = 0; r < 4; ++r) {
        #pragma unroll
        for (int h = 0; h < 2; ++h) {
            const float4 p = P[r][h];
            float4 m = make_float4(0.f, 0.f, 0.f, 0.f);
            if (have) m = mrow4[r * 128 + h * 64 + lane];
            const float pv[4] = {p.x, p.y, p.z, p.w};
            const float mv[4] = {m.x, m.y, m.z, m.w};
            #pragma unroll
            for (int j = 0; j < 4; ++j) {
                const float lp = __log2f(pv[j]);
                const float l1 = __log2f(1.0f - pv[j]);
                acc += l1 + mv[j] * (lp - l1);
            }
        }
    }
    acc *= LN2;   // one natural-log scale per wave

    // ---- wave reduction -> per-task partial ----
    #pragma unroll
    for (int off = 32; off; off >>= 1) acc += __shfl_down(acc, off, 64);
    if (lane == 0) wave_sums[task] = acc;
}

// ---------------------------------------------------------------------------
// Fused tail: per-image reduce of 128 task partials + any_valid gate +
// batch mean. One block, 1024 threads (32 workers/image); shuffle reductions.
// ---------------------------------------------------------------------------
__global__ __launch_bounds__(1024) void final_kernel(
    const float* __restrict__ bboxs,
    const int*   __restrict__ img_h_p,
    const int*   __restrict__ img_w_p,
    const float* __restrict__ wave_sums,
    float*       __restrict__ out)
{
    const int t = threadIdx.x;
    const int b = t >> 5;        // image 0..31 (two images per 64-lane wave)
    const int j = t & 31;        // worker within image

    __shared__ float s_loss[B_];

    float s = 0.0f;
    #pragma unroll
    for (int k = 0; k < 4; ++k) s += wave_sums[b * 128 + j + 32 * k];

    const float fw = (float)(*img_w_p);
    const float fh = (float)(*img_h_p);
    int av = 0;
    const float* bp = bboxs + (size_t)b * N_ * 5;
    #pragma unroll
    for (int n = j * 4; n < j * 4 + 4; ++n) {
        const float c0 = bp[n * 5 + 0];
        const float c1 = bp[n * 5 + 1];
        const float c2 = bp[n * 5 + 2];
        const float c3 = bp[n * 5 + 3];
        const float lab = bp[n * 5 + 4];
        av |= ((lab != -1.0f) && (c0 <= fw) && (c1 <= fh)
                              && (c2 <= fw) && (c3 <= fh)) ? 1 : 0;
    }

    // reduce the 32 workers of each image (half-wave groups)
    #pragma unroll
    for (int off = 16; off; off >>= 1) {
        s  += __shfl_down(s, off, 64);
        av |= __shfl_down(av, off, 64);
    }
    if (j == 0) s_loss[b] = av ? (-s * (1.0f / (float)(AH_ * AW_))) : 0.0f;
    __syncthreads();

    // batch mean: first wave, all 64 lanes live (upper 32 contribute 0)
    if (t < 64) {
        float v = (t < B_) ? s_loss[t] : 0.0f;
        #pragma unroll
        for (int off = 32; off; off >>= 1) v += __shfl_down(v, off, 64);
        if (t == 0) out[0] = v * (1.0f / (float)B_);
    }
}

extern "C" void kernel_launch(void* const* d_in, const int* in_sizes, int n_in,
                              void* d_out, int out_size, void* d_ws, size_t ws_size,
                              hipStream_t stream)
{
    const float* att   = (const float*)d_in[0];   // (32,1,512,512) f32
    const float* bboxs = (const float*)d_in[1];   // (32,128,5) f32
    const int*   img_h = (const int*)d_in[2];     // scalar
    const int*   img_w = (const int*)d_in[3];     // scalar
    float* out = (float*)d_out;
    float* wave_sums = (float*)d_ws;              // 4096 floats (16 KB)

    row_bce_kernel<<<B_ * AH_ / 8, 128, 0, stream>>>(att, bboxs, img_h, img_w, wave_sums);
    final_kernel<<<1, 1024, 0, stream>>>(bboxs, img_h, img_w, wave_sums, out);
}